// Round 17
// baseline (823.028 us; speedup 1.0000x reference)
//
#include <hip/hip_runtime.h>

typedef short short8 __attribute__((ext_vector_type(8)));
typedef float f32x4 __attribute__((ext_vector_type(4)));

#define B_    64
#define CH_   8
#define NBC   512
#define MATU  65536      // elements per padded 256x256 matrix
#define H_    251
#define PADX  76         // conv input tile LDS row stride (floats; 304B = 16B-aligned rows)
#define LDSW  40         // A-plane LDS row stride in ushort (80B): frag reads 2-way max

__device__ inline unsigned short bf16r(float f){
    unsigned u = __float_as_uint(f);
    u += 0x7fffu + ((u >> 16) & 1u);
    return (unsigned short)(u >> 16);
}
__device__ inline float bf16f(unsigned short h){ return __uint_as_float(((unsigned)h) << 16); }
__device__ inline unsigned packsplit(float v){
    unsigned short h = bf16r(v);
    unsigned short l = bf16r(v - bf16f(h));
    return (((unsigned)h) << 16) | (unsigned)l;
}
__device__ inline float unpackf(unsigned u){
    return __uint_as_float(u & 0xffff0000u) + bf16f((unsigned short)(u & 0xffffu));
}

// ---------------- conv: x[b] -> Ypk (packed hi|lo u32, row-major), zero-padded to 256.
// 4 channels per block; row loads hoisted across channels, float4-vectorized. ----------------
__global__ __launch_bounds__(256) void conv_pack(const float* __restrict__ x,
                                                 const float* __restrict__ w,
                                                 const float* __restrict__ bias,
                                                 unsigned* __restrict__ Ypk,
                                                 int b_base) {
    __shared__ float xt[69 * PADX];
    __shared__ float wsm[148];                 // 4*36 weights + 4 bias

    int tid = threadIdx.x;
    int tile = blockIdx.x;                     // 0..15
    int lb = blockIdx.y;                       // local batch in chunk
    int cq = blockIdx.z;                       // channel quad 0..1
    int b = b_base + lb;
    int r0 = (tile >> 2) * 64, c0 = (tile & 3) * 64;

    if (tid < 144) wsm[tid] = w[cq * 144 + tid];
    if (tid < 4)   wsm[144 + tid] = bias[cq * 4 + tid];

    const float* xb = x + (size_t)b * 65536;
    for (int idx = tid; idx < 69 * PADX; idx += 256) {
        int row = idx / PADX, col = idx - row * PADX;
        float v = 0.f;
        if (col < 69) {
            int gr = r0 + row; if (gr > 255) gr = 255;
            int gc = c0 + col; if (gc > 255) gc = 255;
            v = xb[gr * 256 + gc];
        }
        xt[idx] = v;
    }
    __syncthreads();

    int tx = tid & 15, ty = tid >> 4;

    float acc[4][4][4];
    #pragma unroll
    for (int cc = 0; cc < 4; ++cc) {
        float bv = wsm[144 + cc];
        #pragma unroll
        for (int i = 0; i < 4; ++i)
            #pragma unroll
            for (int j = 0; j < 4; ++j) acc[cc][i][j] = bv;
    }

    #pragma unroll
    for (int ir = 0; ir < 9; ++ir) {
        float row[9];
        {
            const float* xr = &xt[(ty * 4 + ir) * PADX + tx * 4];   // 16B-aligned
            float4 ra = *(const float4*)xr;
            float4 rb = *(const float4*)(xr + 4);
            row[0] = ra.x; row[1] = ra.y; row[2] = ra.z; row[3] = ra.w;
            row[4] = rb.x; row[5] = rb.y; row[6] = rb.z; row[7] = rb.w;
            row[8] = xr[8];
        }
        #pragma unroll
        for (int cc = 0; cc < 4; ++cc) {
            const float* wc = &wsm[cc * 36];
            #pragma unroll
            for (int i = 0; i < 4; ++i) {
                int u = ir - i;
                if (u >= 0 && u < 6) {
                    #pragma unroll
                    for (int v = 0; v < 6; ++v) {
                        float wv = wc[u * 6 + v];
                        #pragma unroll
                        for (int j = 0; j < 4; ++j) acc[cc][i][j] += row[j + v] * wv;
                    }
                }
            }
        }
    }

    #pragma unroll
    for (int cc = 0; cc < 4; ++cc) {
        int ch = cq * 4 + cc;
        unsigned pk[4][4];
        #pragma unroll
        for (int i = 0; i < 4; ++i) {
            int gr = r0 + ty * 4 + i;
            #pragma unroll
            for (int j = 0; j < 4; ++j) {
                int gc = c0 + tx * 4 + j;
                float v = (gr < H_ && gc < H_) ? acc[cc][i][j] : 0.f;
                pk[i][j] = packsplit(v);
            }
        }
        unsigned* yrow = Ypk + (size_t)(lb * 8 + ch) * MATU;
        #pragma unroll
        for (int i = 0; i < 4; ++i) {
            uint4 v = make_uint4(pk[i][0], pk[i][1], pk[i][2], pk[i][3]);
            *(uint4*)&yrow[(size_t)(r0 + ty * 4 + i) * 256 + c0 + tx * 4] = v;
        }
    }
}

// ---------------- MFMA GEMM out = X*X (split bf16, 3 chains), X = Apk (row-major packed).
// 128x256 block tile, 8 waves (512 thr), 2 blocks/matrix:
//   A staged [128][LDSW] hi/lo planes; B transpose-staged subtiled [kb:4][col:256][8] hi/lo.
// Per-output MFMA order identical to the 128x128 (r14) structure — geometry-only change.
// PHASE1 (X=Y): writes M row-major; pdiag=t2=tr(M), pfull=t3=sum M_ij*Y_ji
// PHASE2 (X=M): no writes;          pdiag=t4,       pfull=t5=sum (M*M)_ij*Y_ji
template<int PHASE>
__global__ __launch_bounds__(512, 6) void gemm_mfma(const unsigned* __restrict__ Apk,
                                                    const unsigned* __restrict__ Ypk,
                                                    unsigned* __restrict__ Mpk,
                                                    double* __restrict__ pdiag,
                                                    double* __restrict__ pfull,
                                                    int bc_base, int cur) {
    __shared__ __align__(16) char smem[53248];   // Ahi[128][40]us | Alo | Bhi[4][256][8]us | Blo
    __shared__ double redbuf[16];

    unsigned short* Ahi = (unsigned short*)smem;
    unsigned short* Alo = (unsigned short*)(smem + 10240);
    unsigned short* Bhi = (unsigned short*)(smem + 20480);
    unsigned short* Blo = (unsigned short*)(smem + 36864);

    int tid = threadIdx.x;

    // XCD-colocating bijective remap: matrix lm -> 2 blocks on XCD lm-group (cur multiple of 8)
    int hw = blockIdx.x;
    int xcd = hw & 7, s = hw >> 3;
    int mpx = cur >> 3;
    int lbc = xcd * mpx + (s >> 1);
    int t = s & 1;
    int bi = t << 7;
    int bc = bc_base + lbc;

    const unsigned* A = Apk + (size_t)lbc * MATU;

    int wid = tid >> 6, l = tid & 63;
    int wr = wid >> 2, wcc = wid & 3;        // 2 row-groups x 4 col-groups
    int l15 = l & 15, lk = l >> 4;

    f32x4 acc[4][4];
    #pragma unroll
    for (int m = 0; m < 4; ++m)
        #pragma unroll
        for (int n = 0; n < 4; ++n) acc[m][n] = (f32x4){0.f, 0.f, 0.f, 0.f};

    // B-stage mapping: wave grp owns (kq,kb,koff); lane cl owns cols cl+64j (j=0..3)
    const int cl  = tid & 63;
    const int grp = tid >> 6;            // 0..7
    const int kq  = grp * 4;             // 0,4,...,28
    const int kb  = grp >> 1;            // k-block 0..3
    const int koff = (grp & 1) * 4;      // offset within 8-k block

    for (int k0 = 0; k0 < 256; k0 += 32) {
        // ---- A stage: rows bi..bi+127, k0..k0+31, unpack u32 -> hi/lo planes ----
        #pragma unroll
        for (int p = 0; p < 2; ++p) {
            int g = p * 512 + tid;
            int row = g >> 3, chn = g & 7;
            uint4 qa = *(const uint4*)(A + (size_t)(bi + row) * 256 + k0 + chn * 4);
            *(ushort4*)&Ahi[row * LDSW + chn * 4] =
                make_ushort4(qa.x >> 16, qa.y >> 16, qa.z >> 16, qa.w >> 16);
            *(ushort4*)&Alo[row * LDSW + chn * 4] =
                make_ushort4(qa.x & 0xffff, qa.y & 0xffff, qa.z & 0xffff, qa.w & 0xffff);
        }
        // ---- B stage (transpose to subtiled [kb][col:256][8]): dword loads, 2-way LDS writes ----
        {
            const unsigned* Bp = A + (size_t)(k0 + kq) * 256 + cl;
            unsigned d[4][4];
            #pragma unroll
            for (int i = 0; i < 4; ++i)
                #pragma unroll
                for (int j = 0; j < 4; ++j)
                    d[i][j] = Bp[i * 256 + j * 64];
            #pragma unroll
            for (int j = 0; j < 4; ++j) {
                int c = cl + 64 * j;
                *(ushort4*)&Bhi[kb * 2048 + c * 8 + koff] =
                    make_ushort4(d[0][j] >> 16, d[1][j] >> 16, d[2][j] >> 16, d[3][j] >> 16);
                *(ushort4*)&Blo[kb * 2048 + c * 8 + koff] =
                    make_ushort4(d[0][j] & 0xffff, d[1][j] & 0xffff, d[2][j] & 0xffff, d[3][j] & 0xffff);
            }
        }
        __syncthreads();

        short8 ah[4], al[4], bh[4], bl[4];
        #pragma unroll
        for (int m = 0; m < 4; ++m) {
            int r = wr * 64 + m * 16 + l15;
            ah[m] = *(const short8*)&Ahi[r * LDSW + lk * 8];
            al[m] = *(const short8*)&Alo[r * LDSW + lk * 8];
        }
        #pragma unroll
        for (int n = 0; n < 4; ++n) {
            int c = wcc * 64 + n * 16 + l15;
            bh[n] = *(const short8*)&Bhi[lk * 2048 + c * 8];
            bl[n] = *(const short8*)&Blo[lk * 2048 + c * 8];
        }
        #pragma unroll
        for (int m = 0; m < 4; ++m)
            #pragma unroll
            for (int n = 0; n < 4; ++n) {
                acc[m][n] = __builtin_amdgcn_mfma_f32_16x16x32_bf16(ah[m], bh[n], acc[m][n], 0, 0, 0);
                acc[m][n] = __builtin_amdgcn_mfma_f32_16x16x32_bf16(ah[m], bl[n], acc[m][n], 0, 0, 0);
                acc[m][n] = __builtin_amdgcn_mfma_f32_16x16x32_bf16(al[m], bh[n], acc[m][n], 0, 0, 0);
            }
        __syncthreads();
    }

    // ---- epilogue: partial traces (+ M write in PHASE1); Y_ji read from row-major Y (contiguous 16B) ----
    const unsigned* Yb = Ypk + (size_t)lbc * MATU;
    unsigned* Mw = (PHASE == 1) ? (Mpk + (size_t)lbc * MATU) : nullptr;
    float s_full = 0.f, s_diag = 0.f;
    #pragma unroll
    for (int m = 0; m < 4; ++m) {
        int rg0 = bi + wr * 64 + m * 16 + lk * 4;
        #pragma unroll
        for (int n = 0; n < 4; ++n) {
            int cg = wcc * 64 + n * 16 + l15;
            uint4 yq = *(const uint4*)(Yb + (size_t)cg * 256 + rg0);   // Y[cg][rg0..rg0+3]
            unsigned yu[4] = {yq.x, yq.y, yq.z, yq.w};
            f32x4 v = acc[m][n];
            #pragma unroll
            for (int reg = 0; reg < 4; ++reg) {
                float val = v[reg];
                s_full += val * unpackf(yu[reg]);
                if (rg0 + reg == cg) s_diag += val;
                if (PHASE == 1) Mw[(size_t)(rg0 + reg) * 256 + cg] = packsplit(val);
            }
        }
    }

    // reduce partials (8 waves)
    double df = (double)s_full, dd = (double)s_diag;
    #pragma unroll
    for (int off = 32; off > 0; off >>= 1) {
        df += __shfl_down(df, off, 64);
        dd += __shfl_down(dd, off, 64);
    }
    __syncthreads();
    if (l == 0) { redbuf[wid] = df; redbuf[8 + wid] = dd; }
    __syncthreads();
    if (tid == 0) {
        double sf = 0.0, sd = 0.0;
        #pragma unroll
        for (int wv = 0; wv < 8; ++wv) { sf += redbuf[wv]; sd += redbuf[8 + wv]; }
        pfull[(size_t)bc * 2 + t] = sf;
        pdiag[(size_t)bc * 2 + t] = sd;
    }
}

// ---------------- combine ----------------
__global__ void combine(const double* __restrict__ p2, const double* __restrict__ p3,
                        const double* __restrict__ p4, const double* __restrict__ p5,
                        const float* __restrict__ coef, float* __restrict__ out) {
    int b = threadIdx.x;
    if (b >= B_) return;
    const double numel = (double)(H_ * H_);
    double acc = 0.0;
    for (int ch = 0; ch < CH_; ++ch) {
        int bc = b * CH_ + ch;
        double t[4];
        t[0] = p2[bc * 2] + p2[bc * 2 + 1];
        t[1] = p3[bc * 2] + p3[bc * 2 + 1];
        t[2] = p4[bc * 2] + p4[bc * 2 + 1];
        t[3] = p5[bc * 2] + p5[bc * 2 + 1];
        double npow_i = numel;
        for (int i = 0; i < 4; ++i) {
            double tv = t[i];
            double p = tv, d = npow_i;
            for (int j = 0; j < 3; ++j) {
                acc += (double)coef[ch * 12 + i * 3 + j] * (p / d);
                p *= tv;
                d *= numel;
            }
            npow_i *= numel;
        }
    }
    out[b] = (float)acc;
}

extern "C" void kernel_launch(void* const* d_in, const int* in_sizes, int n_in,
                              void* d_out, int out_size, void* d_ws, size_t ws_size,
                              hipStream_t stream) {
    const float* x    = (const float*)d_in[0];
    const float* w    = (const float*)d_in[1];
    const float* bias = (const float*)d_in[2];
    const float* coef = (const float*)d_in[3];
    float* out = (float*)d_out;

    // head: p2/p3/p4/p5 each [512][2] doubles (8KB each, 32KB total) in first 64KB
    double* p2 = (double*)d_ws;
    double* p3 = p2 + NBC * 2;
    double* p4 = p3 + NBC * 2;
    double* p5 = p4 + NBC * 2;
    const size_t head = 65536;

    const size_t per_mat = (size_t)MATU * 4;                 // 256 KB per packed matrix plane
    size_t avail = (ws_size > head) ? ws_size - head : 0;
    int NC = (int)(avail / (2 * per_mat));                   // Y + M per matrix (512 KB)
    NC &= ~7;                                                // whole batches of 8 channels
    if (NC > 256) NC = 256;                                  // chunk WS <= 128MB (proven-safe)
    if (NC < 8) NC = 8;

    unsigned* Ypk = (unsigned*)((char*)d_ws + head);
    unsigned* Mpk = Ypk + (size_t)NC * MATU;

    for (int bc0 = 0; bc0 < NBC; bc0 += NC) {
        int cur = NBC - bc0;
        if (cur > NC) cur = NC;
        int nb = cur / 8;
        conv_pack<<<dim3(16, nb, 2), 256, 0, stream>>>(x, w, bias, Ypk, bc0 / 8);
        // G1: M = Y*Y ; t2 = tr(M), t3 = sum M_ij * Y_ji
        gemm_mfma<1><<<cur * 2, 512, 0, stream>>>(Ypk, Ypk, Mpk, p2, p3, bc0, cur);
        // G2: P = M*M ; t4 = tr(P), t5 = sum P_ij * Y_ji
        gemm_mfma<2><<<cur * 2, 512, 0, stream>>>(Mpk, Ypk, nullptr, p4, p5, bc0, cur);
    }
    combine<<<1, 64, 0, stream>>>(p2, p3, p4, p5, coef, out);
}

// Round 18
// 228.498 us; speedup vs baseline: 3.6019x; 3.6019x over previous
//
#include <hip/hip_runtime.h>

typedef short short8 __attribute__((ext_vector_type(8)));
typedef float f32x4 __attribute__((ext_vector_type(4)));

#define B_    64
#define CH_   8
#define NBC   512
#define MATU  65536      // elements per padded 256x256 matrix
#define H_    251
#define PADX  76         // conv input tile LDS row stride (floats; 304B = 16B-aligned rows)
#define LDSW  40         // A-plane LDS row stride in ushort (80B): frag reads 2-way max

__device__ inline unsigned short bf16r(float f){
    unsigned u = __float_as_uint(f);
    u += 0x7fffu + ((u >> 16) & 1u);
    return (unsigned short)(u >> 16);
}
__device__ inline float bf16f(unsigned short h){ return __uint_as_float(((unsigned)h) << 16); }
__device__ inline unsigned packsplit(float v){
    unsigned short h = bf16r(v);
    unsigned short l = bf16r(v - bf16f(h));
    return (((unsigned)h) << 16) | (unsigned)l;
}
__device__ inline float unpackf(unsigned u){
    return __uint_as_float(u & 0xffff0000u) + bf16f((unsigned short)(u & 0xffffu));
}

// ---------------- conv: x[b] -> Ypk (packed hi|lo u32, row-major), zero-padded to 256.
// 4 channels per block; row loads hoisted across channels, float4-vectorized.
// x-tile staged as float4 chunks: each chunk fully in-range or fully OOB (-> 0), since
// c0/r0 are multiples of 64 (outputs needing OOB inputs are zeroed in the epilogue anyway).
__global__ __launch_bounds__(256) void conv_pack(const float* __restrict__ x,
                                                 const float* __restrict__ w,
                                                 const float* __restrict__ bias,
                                                 unsigned* __restrict__ Ypk,
                                                 int b_base) {
    __shared__ float xt[69 * PADX];
    __shared__ float wsm[148];                 // 4*36 weights + 4 bias

    int tid = threadIdx.x;
    int tile = blockIdx.x;                     // 0..15
    int lb = blockIdx.y;                       // local batch in chunk
    int cq = blockIdx.z;                       // channel quad 0..1
    int b = b_base + lb;
    int r0 = (tile >> 2) * 64, c0 = (tile & 3) * 64;

    if (tid < 144) wsm[tid] = w[cq * 144 + tid];
    if (tid < 4)   wsm[144 + tid] = bias[cq * 4 + tid];

    const float* xb = x + (size_t)b * 65536;
    // 69 rows x 19 float4-chunks = 1311 items, 6 iterations
    for (int idx = tid; idx < 69 * 19; idx += 256) {
        int row = idx / 19, chq = idx - row * 19;
        int gr = r0 + row, gc = c0 + chq * 4;
        float4 v = make_float4(0.f, 0.f, 0.f, 0.f);
        if (gr < 256 && gc < 256) v = *(const float4*)(xb + gr * 256 + gc);
        *(float4*)&xt[row * PADX + chq * 4] = v;
    }
    __syncthreads();

    int tx = tid & 15, ty = tid >> 4;

    float acc[4][4][4];
    #pragma unroll
    for (int cc = 0; cc < 4; ++cc) {
        float bv = wsm[144 + cc];
        #pragma unroll
        for (int i = 0; i < 4; ++i)
            #pragma unroll
            for (int j = 0; j < 4; ++j) acc[cc][i][j] = bv;
    }

    #pragma unroll
    for (int ir = 0; ir < 9; ++ir) {
        float row[9];
        {
            const float* xr = &xt[(ty * 4 + ir) * PADX + tx * 4];   // 16B-aligned
            float4 ra = *(const float4*)xr;
            float4 rb = *(const float4*)(xr + 4);
            row[0] = ra.x; row[1] = ra.y; row[2] = ra.z; row[3] = ra.w;
            row[4] = rb.x; row[5] = rb.y; row[6] = rb.z; row[7] = rb.w;
            row[8] = xr[8];
        }
        #pragma unroll
        for (int cc = 0; cc < 4; ++cc) {
            const float* wc = &wsm[cc * 36];
            #pragma unroll
            for (int i = 0; i < 4; ++i) {
                int u = ir - i;
                if (u >= 0 && u < 6) {
                    #pragma unroll
                    for (int v = 0; v < 6; ++v) {
                        float wv = wc[u * 6 + v];
                        #pragma unroll
                        for (int j = 0; j < 4; ++j) acc[cc][i][j] += row[j + v] * wv;
                    }
                }
            }
        }
    }

    #pragma unroll
    for (int cc = 0; cc < 4; ++cc) {
        int ch = cq * 4 + cc;
        unsigned pk[4][4];
        #pragma unroll
        for (int i = 0; i < 4; ++i) {
            int gr = r0 + ty * 4 + i;
            #pragma unroll
            for (int j = 0; j < 4; ++j) {
                int gc = c0 + tx * 4 + j;
                float v = (gr < H_ && gc < H_) ? acc[cc][i][j] : 0.f;
                pk[i][j] = packsplit(v);
            }
        }
        unsigned* yrow = Ypk + (size_t)(lb * 8 + ch) * MATU;
        #pragma unroll
        for (int i = 0; i < 4; ++i) {
            uint4 v = make_uint4(pk[i][0], pk[i][1], pk[i][2], pk[i][3]);
            *(uint4*)&yrow[(size_t)(r0 + ty * 4 + i) * 256 + c0 + tx * 4] = v;
        }
    }
}

// ---------------- MFMA GEMM out = X*X (split bf16, 3 chains), X = Apk (row-major packed).
// A staged in [128][LDSW] planes; B transpose-staged into subtiled [kb:4][col:128][8] planes
// (dword global loads, 2-way-max LDS writes, sequential b128 frag reads).
// LDS right-sized to 36864B -> 4 blocks/CU (r14/r16-proven structure).
// PHASE1 (X=Y): writes M row-major; pdiag=t2=tr(M), pfull=t3=sum M_ij*Y_ji
// PHASE2 (X=M): no writes;          pdiag=t4,       pfull=t5=sum (M*M)_ij*Y_ji
template<int PHASE>
__global__ __launch_bounds__(256, 4) void gemm_mfma(const unsigned* __restrict__ Apk,
                                                    const unsigned* __restrict__ Ypk,
                                                    unsigned* __restrict__ Mpk,
                                                    double* __restrict__ pdiag,
                                                    double* __restrict__ pfull,
                                                    int bc_base, int cur) {
    __shared__ __align__(16) char smem[36864];   // Ahi[128][40]us | Alo[128][40]us | Bhi[4][128][8]us | Blo[4][128][8]us
    __shared__ double redbuf[8];

    unsigned short* Ahi = (unsigned short*)smem;
    unsigned short* Alo = (unsigned short*)(smem + 10240);
    unsigned short* Bhi = (unsigned short*)(smem + 20480);
    unsigned short* Blo = (unsigned short*)(smem + 28672);

    int tid = threadIdx.x;

    // XCD-colocating bijective remap (cur always a multiple of 8)
    int hw = blockIdx.x;
    int xcd = hw & 7, s = hw >> 3;
    int mpx = cur >> 3;
    int lbc = xcd * mpx + (s >> 2);
    int t4 = s & 3;
    int by = t4 >> 1, bx = t4 & 1;
    int bi = by * 128, bj = bx * 128;
    int bc = bc_base + lbc;

    const unsigned* A = Apk + (size_t)lbc * MATU;

    int wid = tid >> 6, l = tid & 63;
    int wr = wid >> 1, wc = wid & 1;
    int l15 = l & 15, lk = l >> 4;

    f32x4 acc[4][4];
    #pragma unroll
    for (int m = 0; m < 4; ++m)
        #pragma unroll
        for (int n = 0; n < 4; ++n) acc[m][n] = (f32x4){0.f, 0.f, 0.f, 0.f};

    // B-stage mapping: lane owns cols cl+32j (j=0..3), ks kq..kq+3
    const int cl  = tid & 31;
    const int grp = tid >> 5;            // 0..7
    const int kq  = grp * 4;             // 0,4,...,28
    const int kb  = grp >> 1;            // k-block 0..3
    const int koff = (grp & 1) * 4;      // offset within 8-k block

    for (int k0 = 0; k0 < 256; k0 += 32) {
        // ---- A stage: rows bi..bi+127, k0..k0+31, unpack u32 -> hi/lo planes ----
        #pragma unroll
        for (int p = 0; p < 4; ++p) {
            int g = p * 256 + tid;
            int row = g >> 3, chn = g & 7;
            uint4 qa = *(const uint4*)(A + (size_t)(bi + row) * 256 + k0 + chn * 4);
            *(ushort4*)&Ahi[row * LDSW + chn * 4] =
                make_ushort4(qa.x >> 16, qa.y >> 16, qa.z >> 16, qa.w >> 16);
            *(ushort4*)&Alo[row * LDSW + chn * 4] =
                make_ushort4(qa.x & 0xffff, qa.y & 0xffff, qa.z & 0xffff, qa.w & 0xffff);
        }
        // ---- B stage (transpose to subtiled [kb][col][8]): dword loads, floor-rate LDS writes ----
        {
            const unsigned* Bp = A + (size_t)(k0 + kq) * 256 + bj + cl;
            unsigned d[4][4];
            #pragma unroll
            for (int i = 0; i < 4; ++i)
                #pragma unroll
                for (int j = 0; j < 4; ++j)
                    d[i][j] = Bp[i * 256 + j * 32];
            #pragma unroll
            for (int j = 0; j < 4; ++j) {
                int c = cl + 32 * j;
                *(ushort4*)&Bhi[kb * 1024 + c * 8 + koff] =
                    make_ushort4(d[0][j] >> 16, d[1][j] >> 16, d[2][j] >> 16, d[3][j] >> 16);
                *(ushort4*)&Blo[kb * 1024 + c * 8 + koff] =
                    make_ushort4(d[0][j] & 0xffff, d[1][j] & 0xffff, d[2][j] & 0xffff, d[3][j] & 0xffff);
            }
        }
        __syncthreads();

        short8 ah[4], al[4], bh[4], bl[4];
        #pragma unroll
        for (int m = 0; m < 4; ++m) {
            int r = wr * 64 + m * 16 + l15;
            ah[m] = *(const short8*)&Ahi[r * LDSW + lk * 8];
            al[m] = *(const short8*)&Alo[r * LDSW + lk * 8];
        }
        #pragma unroll
        for (int n = 0; n < 4; ++n) {
            int c = wc * 64 + n * 16 + l15;
            bh[n] = *(const short8*)&Bhi[lk * 1024 + c * 8];
            bl[n] = *(const short8*)&Blo[lk * 1024 + c * 8];
        }
        #pragma unroll
        for (int m = 0; m < 4; ++m)
            #pragma unroll
            for (int n = 0; n < 4; ++n) {
                acc[m][n] = __builtin_amdgcn_mfma_f32_16x16x32_bf16(ah[m], bh[n], acc[m][n], 0, 0, 0);
                acc[m][n] = __builtin_amdgcn_mfma_f32_16x16x32_bf16(ah[m], bl[n], acc[m][n], 0, 0, 0);
                acc[m][n] = __builtin_amdgcn_mfma_f32_16x16x32_bf16(al[m], bh[n], acc[m][n], 0, 0, 0);
            }
        __syncthreads();
    }

    // ---- epilogue: partial traces (+ M write in PHASE1); Y_ji read from row-major Y (contiguous 16B) ----
    const unsigned* Yb = Ypk + (size_t)lbc * MATU;
    unsigned* Mw = (PHASE == 1) ? (Mpk + (size_t)lbc * MATU) : nullptr;
    float s_full = 0.f, s_diag = 0.f;
    #pragma unroll
    for (int m = 0; m < 4; ++m) {
        int rg0 = bi + wr * 64 + m * 16 + lk * 4;
        #pragma unroll
        for (int n = 0; n < 4; ++n) {
            int cg = bj + wc * 64 + n * 16 + l15;
            uint4 yq = *(const uint4*)(Yb + (size_t)cg * 256 + rg0);   // Y[cg][rg0..rg0+3]
            unsigned yu[4] = {yq.x, yq.y, yq.z, yq.w};
            f32x4 v = acc[m][n];
            #pragma unroll
            for (int reg = 0; reg < 4; ++reg) {
                float val = v[reg];
                s_full += val * unpackf(yu[reg]);
                if (rg0 + reg == cg) s_diag += val;
                if (PHASE == 1) Mw[(size_t)(rg0 + reg) * 256 + cg] = packsplit(val);
            }
        }
    }

    // reduce partials
    double df = (double)s_full, dd = (double)s_diag;
    #pragma unroll
    for (int off = 32; off > 0; off >>= 1) {
        df += __shfl_down(df, off, 64);
        dd += __shfl_down(dd, off, 64);
    }
    __syncthreads();
    if (l == 0) { redbuf[wid] = df; redbuf[4 + wid] = dd; }
    __syncthreads();
    if (tid == 0) {
        pfull[(size_t)bc * 4 + by * 2 + bx] =
            redbuf[0] + redbuf[1] + redbuf[2] + redbuf[3];
        if (bx == by)
            pdiag[(size_t)bc * 2 + bx] =
                redbuf[4] + redbuf[5] + redbuf[6] + redbuf[7];
    }
}

// ---------------- combine ----------------
__global__ void combine(const double* __restrict__ p2, const double* __restrict__ p3,
                        const double* __restrict__ p4, const double* __restrict__ p5,
                        const float* __restrict__ coef, float* __restrict__ out) {
    int b = threadIdx.x;
    if (b >= B_) return;
    const double numel = (double)(H_ * H_);
    double acc = 0.0;
    for (int ch = 0; ch < CH_; ++ch) {
        int bc = b * CH_ + ch;
        double t[4];
        t[0] = p2[bc * 2] + p2[bc * 2 + 1];
        t[1] = p3[bc * 4] + p3[bc * 4 + 1] + p3[bc * 4 + 2] + p3[bc * 4 + 3];
        t[2] = p4[bc * 2] + p4[bc * 2 + 1];
        t[3] = p5[bc * 4] + p5[bc * 4 + 1] + p5[bc * 4 + 2] + p5[bc * 4 + 3];
        double npow_i = numel;
        for (int i = 0; i < 4; ++i) {
            double tv = t[i];
            double p = tv, d = npow_i;
            for (int j = 0; j < 3; ++j) {
                acc += (double)coef[ch * 12 + i * 3 + j] * (p / d);
                p *= tv;
                d *= numel;
            }
            npow_i *= numel;
        }
    }
    out[b] = (float)acc;
}

extern "C" void kernel_launch(void* const* d_in, const int* in_sizes, int n_in,
                              void* d_out, int out_size, void* d_ws, size_t ws_size,
                              hipStream_t stream) {
    const float* x    = (const float*)d_in[0];
    const float* w    = (const float*)d_in[1];
    const float* bias = (const float*)d_in[2];
    const float* coef = (const float*)d_in[3];
    float* out = (float*)d_out;

    // head: p2[512*2] p3[512*4] p4[512*2] p5[512*4] doubles (48KB) in first 64KB
    double* p2 = (double*)d_ws;
    double* p3 = p2 + NBC * 2;
    double* p4 = p3 + NBC * 4;
    double* p5 = p4 + NBC * 2;
    const size_t head = 65536;

    const size_t per_mat = (size_t)MATU * 4;                 // 256 KB per packed matrix plane
    size_t avail = (ws_size > head) ? ws_size - head : 0;
    int NC = (int)(avail / (2 * per_mat));                   // Y + M per matrix (512 KB)
    NC &= ~7;                                                // whole batches of 8 channels
    if (NC > 256) NC = 256;                                  // chunk WS <= 128MB (proven-safe)
    if (NC < 8) NC = 8;

    unsigned* Ypk = (unsigned*)((char*)d_ws + head);
    unsigned* Mpk = Ypk + (size_t)NC * MATU;

    for (int bc0 = 0; bc0 < NBC; bc0 += NC) {
        int cur = NBC - bc0;
        if (cur > NC) cur = NC;
        int nb = cur / 8;
        conv_pack<<<dim3(16, nb, 2), 256, 0, stream>>>(x, w, bias, Ypk, bc0 / 8);
        // G1: M = Y*Y ; t2 = tr(M), t3 = sum M_ij * Y_ji
        gemm_mfma<1><<<cur * 4, 256, 0, stream>>>(Ypk, Ypk, Mpk, p2, p3, bc0, cur);
        // G2: P = M*M ; t4 = tr(P), t5 = sum P_ij * Y_ji
        gemm_mfma<2><<<cur * 4, 256, 0, stream>>>(Mpk, Ypk, nullptr, p4, p5, bc0, cur);
    }
    combine<<<1, 64, 0, stream>>>(p2, p3, p4, p5, coef, out);
}

// Round 19
// 227.137 us; speedup vs baseline: 3.6235x; 1.0060x over previous
//
#include <hip/hip_runtime.h>

typedef short short8 __attribute__((ext_vector_type(8)));
typedef float f32x4 __attribute__((ext_vector_type(4)));

#define B_    64
#define CH_   8
#define NBC   512
#define MATU  65536      // elements per padded 256x256 matrix
#define H_    251
#define PADX  76         // conv input tile LDS row stride (floats; 304B = 16B-aligned rows)
#define LDSW  40         // A-plane LDS row stride in ushort (80B): frag reads 2-way max

#define SEL_HI 0x07060302u   // perm(y,x,SEL_HI) = (hi16(y)<<16)|hi16(x)
#define SEL_LO 0x05040100u   // perm(y,x,SEL_LO) = (lo16(y)<<16)|lo16(x)

__device__ inline unsigned short bf16r(float f){
    unsigned u = __float_as_uint(f);
    u += 0x7fffu + ((u >> 16) & 1u);
    return (unsigned short)(u >> 16);
}
__device__ inline float bf16f(unsigned short h){ return __uint_as_float(((unsigned)h) << 16); }
__device__ inline unsigned packsplit(float v){
    unsigned short h = bf16r(v);
    unsigned short l = bf16r(v - bf16f(h));
    return (((unsigned)h) << 16) | (unsigned)l;
}
__device__ inline float unpackf(unsigned u){
    return __uint_as_float(u & 0xffff0000u) + bf16f((unsigned short)(u & 0xffffu));
}

// ---------------- conv: x[b] -> Ypk (packed hi|lo u32, row-major), zero-padded to 256.
// 4 channels per block; row loads hoisted across channels, float4-vectorized staging. ----------------
__global__ __launch_bounds__(256) void conv_pack(const float* __restrict__ x,
                                                 const float* __restrict__ w,
                                                 const float* __restrict__ bias,
                                                 unsigned* __restrict__ Ypk,
                                                 int b_base) {
    __shared__ float xt[69 * PADX];
    __shared__ float wsm[148];                 // 4*36 weights + 4 bias

    int tid = threadIdx.x;
    int tile = blockIdx.x;                     // 0..15
    int lb = blockIdx.y;                       // local batch in chunk
    int cq = blockIdx.z;                       // channel quad 0..1
    int b = b_base + lb;
    int r0 = (tile >> 2) * 64, c0 = (tile & 3) * 64;

    if (tid < 144) wsm[tid] = w[cq * 144 + tid];
    if (tid < 4)   wsm[144 + tid] = bias[cq * 4 + tid];

    const float* xb = x + (size_t)b * 65536;
    // 69 rows x 19 float4-chunks = 1311 items, 6 iterations; chunks fully in-range or fully OOB->0
    for (int idx = tid; idx < 69 * 19; idx += 256) {
        int row = idx / 19, chq = idx - row * 19;
        int gr = r0 + row, gc = c0 + chq * 4;
        float4 v = make_float4(0.f, 0.f, 0.f, 0.f);
        if (gr < 256 && gc < 256) v = *(const float4*)(xb + gr * 256 + gc);
        *(float4*)&xt[row * PADX + chq * 4] = v;
    }
    __syncthreads();

    int tx = tid & 15, ty = tid >> 4;

    float acc[4][4][4];
    #pragma unroll
    for (int cc = 0; cc < 4; ++cc) {
        float bv = wsm[144 + cc];
        #pragma unroll
        for (int i = 0; i < 4; ++i)
            #pragma unroll
            for (int j = 0; j < 4; ++j) acc[cc][i][j] = bv;
    }

    #pragma unroll
    for (int ir = 0; ir < 9; ++ir) {
        float row[9];
        {
            const float* xr = &xt[(ty * 4 + ir) * PADX + tx * 4];   // 16B-aligned
            float4 ra = *(const float4*)xr;
            float4 rb = *(const float4*)(xr + 4);
            row[0] = ra.x; row[1] = ra.y; row[2] = ra.z; row[3] = ra.w;
            row[4] = rb.x; row[5] = rb.y; row[6] = rb.z; row[7] = rb.w;
            row[8] = xr[8];
        }
        #pragma unroll
        for (int cc = 0; cc < 4; ++cc) {
            const float* wc = &wsm[cc * 36];
            #pragma unroll
            for (int i = 0; i < 4; ++i) {
                int u = ir - i;
                if (u >= 0 && u < 6) {
                    #pragma unroll
                    for (int v = 0; v < 6; ++v) {
                        float wv = wc[u * 6 + v];
                        #pragma unroll
                        for (int j = 0; j < 4; ++j) acc[cc][i][j] += row[j + v] * wv;
                    }
                }
            }
        }
    }

    #pragma unroll
    for (int cc = 0; cc < 4; ++cc) {
        int ch = cq * 4 + cc;
        unsigned pk[4][4];
        #pragma unroll
        for (int i = 0; i < 4; ++i) {
            int gr = r0 + ty * 4 + i;
            #pragma unroll
            for (int j = 0; j < 4; ++j) {
                int gc = c0 + tx * 4 + j;
                float v = (gr < H_ && gc < H_) ? acc[cc][i][j] : 0.f;
                pk[i][j] = packsplit(v);
            }
        }
        unsigned* yrow = Ypk + (size_t)(lb * 8 + ch) * MATU;
        #pragma unroll
        for (int i = 0; i < 4; ++i) {
            uint4 v = make_uint4(pk[i][0], pk[i][1], pk[i][2], pk[i][3]);
            *(uint4*)&yrow[(size_t)(r0 + ty * 4 + i) * 256 + c0 + tx * 4] = v;
        }
    }
}

// ---------------- MFMA GEMM out = X*X (split bf16, 3 chains), X = Apk (row-major packed).
// A staged in [128][LDSW] planes; B transpose-staged into subtiled [kb:4][col:128][8] planes.
// hi/lo unpack via v_perm_b32 (2 instr / 2 dwords, bit-exact) instead of shift/and/pack.
// PHASE1 (X=Y): writes M row-major; pdiag=t2=tr(M), pfull=t3=sum M_ij*Y_ji
// PHASE2 (X=M): no writes;          pdiag=t4,       pfull=t5=sum (M*M)_ij*Y_ji
template<int PHASE>
__global__ __launch_bounds__(256, 4) void gemm_mfma(const unsigned* __restrict__ Apk,
                                                    const unsigned* __restrict__ Ypk,
                                                    unsigned* __restrict__ Mpk,
                                                    double* __restrict__ pdiag,
                                                    double* __restrict__ pfull,
                                                    int bc_base, int cur) {
    __shared__ __align__(16) char smem[36864];   // Ahi[128][40]us | Alo[128][40]us | Bhi[4][128][8]us | Blo[4][128][8]us
    __shared__ double redbuf[8];

    unsigned short* Ahi = (unsigned short*)smem;
    unsigned short* Alo = (unsigned short*)(smem + 10240);
    unsigned short* Bhi = (unsigned short*)(smem + 20480);
    unsigned short* Blo = (unsigned short*)(smem + 28672);

    int tid = threadIdx.x;

    // XCD-colocating bijective remap (cur always a multiple of 8)
    int hw = blockIdx.x;
    int xcd = hw & 7, s = hw >> 3;
    int mpx = cur >> 3;
    int lbc = xcd * mpx + (s >> 2);
    int t4 = s & 3;
    int by = t4 >> 1, bx = t4 & 1;
    int bi = by * 128, bj = bx * 128;
    int bc = bc_base + lbc;

    const unsigned* A = Apk + (size_t)lbc * MATU;

    int wid = tid >> 6, l = tid & 63;
    int wr = wid >> 1, wc = wid & 1;
    int l15 = l & 15, lk = l >> 4;

    f32x4 acc[4][4];
    #pragma unroll
    for (int m = 0; m < 4; ++m)
        #pragma unroll
        for (int n = 0; n < 4; ++n) acc[m][n] = (f32x4){0.f, 0.f, 0.f, 0.f};

    // B-stage mapping: lane owns cols cl+32j (j=0..3), ks kq..kq+3
    const int cl  = tid & 31;
    const int grp = tid >> 5;            // 0..7
    const int kq  = grp * 4;             // 0,4,...,28
    const int kb  = grp >> 1;            // k-block 0..3
    const int koff = (grp & 1) * 4;      // offset within 8-k block

    for (int k0 = 0; k0 < 256; k0 += 32) {
        // ---- A stage: rows bi..bi+127, k0..k0+31, unpack u32 -> hi/lo planes via v_perm ----
        #pragma unroll
        for (int p = 0; p < 4; ++p) {
            int g = p * 256 + tid;
            int row = g >> 3, chn = g & 7;
            uint4 qa = *(const uint4*)(A + (size_t)(bi + row) * 256 + k0 + chn * 4);
            uint2 hv, lv;
            hv.x = __builtin_amdgcn_perm(qa.y, qa.x, SEL_HI);
            hv.y = __builtin_amdgcn_perm(qa.w, qa.z, SEL_HI);
            lv.x = __builtin_amdgcn_perm(qa.y, qa.x, SEL_LO);
            lv.y = __builtin_amdgcn_perm(qa.w, qa.z, SEL_LO);
            *(uint2*)&Ahi[row * LDSW + chn * 4] = hv;
            *(uint2*)&Alo[row * LDSW + chn * 4] = lv;
        }
        // ---- B stage (transpose to subtiled [kb][col][8]): dword loads, perm repack, 2-way LDS writes ----
        {
            const unsigned* Bp = A + (size_t)(k0 + kq) * 256 + bj + cl;
            unsigned d[4][4];
            #pragma unroll
            for (int i = 0; i < 4; ++i)
                #pragma unroll
                for (int j = 0; j < 4; ++j)
                    d[i][j] = Bp[i * 256 + j * 32];
            #pragma unroll
            for (int j = 0; j < 4; ++j) {
                int c = cl + 32 * j;
                uint2 hv, lv;
                hv.x = __builtin_amdgcn_perm(d[1][j], d[0][j], SEL_HI);
                hv.y = __builtin_amdgcn_perm(d[3][j], d[2][j], SEL_HI);
                lv.x = __builtin_amdgcn_perm(d[1][j], d[0][j], SEL_LO);
                lv.y = __builtin_amdgcn_perm(d[3][j], d[2][j], SEL_LO);
                *(uint2*)&Bhi[kb * 1024 + c * 8 + koff] = hv;
                *(uint2*)&Blo[kb * 1024 + c * 8 + koff] = lv;
            }
        }
        __syncthreads();

        short8 ah[4], al[4], bh[4], bl[4];
        #pragma unroll
        for (int m = 0; m < 4; ++m) {
            int r = wr * 64 + m * 16 + l15;
            ah[m] = *(const short8*)&Ahi[r * LDSW + lk * 8];
            al[m] = *(const short8*)&Alo[r * LDSW + lk * 8];
        }
        #pragma unroll
        for (int n = 0; n < 4; ++n) {
            int c = wc * 64 + n * 16 + l15;
            bh[n] = *(const short8*)&Bhi[lk * 1024 + c * 8];
            bl[n] = *(const short8*)&Blo[lk * 1024 + c * 8];
        }
        #pragma unroll
        for (int m = 0; m < 4; ++m)
            #pragma unroll
            for (int n = 0; n < 4; ++n) {
                acc[m][n] = __builtin_amdgcn_mfma_f32_16x16x32_bf16(ah[m], bh[n], acc[m][n], 0, 0, 0);
                acc[m][n] = __builtin_amdgcn_mfma_f32_16x16x32_bf16(ah[m], bl[n], acc[m][n], 0, 0, 0);
                acc[m][n] = __builtin_amdgcn_mfma_f32_16x16x32_bf16(al[m], bh[n], acc[m][n], 0, 0, 0);
            }
        __syncthreads();
    }

    // ---- epilogue: partial traces (+ M write in PHASE1); Y_ji read from row-major Y (contiguous 16B) ----
    const unsigned* Yb = Ypk + (size_t)lbc * MATU;
    unsigned* Mw = (PHASE == 1) ? (Mpk + (size_t)lbc * MATU) : nullptr;
    float s_full = 0.f, s_diag = 0.f;
    #pragma unroll
    for (int m = 0; m < 4; ++m) {
        int rg0 = bi + wr * 64 + m * 16 + lk * 4;
        #pragma unroll
        for (int n = 0; n < 4; ++n) {
            int cg = bj + wc * 64 + n * 16 + l15;
            uint4 yq = *(const uint4*)(Yb + (size_t)cg * 256 + rg0);   // Y[cg][rg0..rg0+3]
            unsigned yu[4] = {yq.x, yq.y, yq.z, yq.w};
            f32x4 v = acc[m][n];
            #pragma unroll
            for (int reg = 0; reg < 4; ++reg) {
                float val = v[reg];
                s_full += val * unpackf(yu[reg]);
                if (rg0 + reg == cg) s_diag += val;
                if (PHASE == 1) Mw[(size_t)(rg0 + reg) * 256 + cg] = packsplit(val);
            }
        }
    }

    // reduce partials
    double df = (double)s_full, dd = (double)s_diag;
    #pragma unroll
    for (int off = 32; off > 0; off >>= 1) {
        df += __shfl_down(df, off, 64);
        dd += __shfl_down(dd, off, 64);
    }
    __syncthreads();
    if (l == 0) { redbuf[wid] = df; redbuf[4 + wid] = dd; }
    __syncthreads();
    if (tid == 0) {
        pfull[(size_t)bc * 4 + by * 2 + bx] =
            redbuf[0] + redbuf[1] + redbuf[2] + redbuf[3];
        if (bx == by)
            pdiag[(size_t)bc * 2 + bx] =
                redbuf[4] + redbuf[5] + redbuf[6] + redbuf[7];
    }
}

// ---------------- combine ----------------
__global__ void combine(const double* __restrict__ p2, const double* __restrict__ p3,
                        const double* __restrict__ p4, const double* __restrict__ p5,
                        const float* __restrict__ coef, float* __restrict__ out) {
    int b = threadIdx.x;
    if (b >= B_) return;
    const double numel = (double)(H_ * H_);
    double acc = 0.0;
    for (int ch = 0; ch < CH_; ++ch) {
        int bc = b * CH_ + ch;
        double t[4];
        t[0] = p2[bc * 2] + p2[bc * 2 + 1];
        t[1] = p3[bc * 4] + p3[bc * 4 + 1] + p3[bc * 4 + 2] + p3[bc * 4 + 3];
        t[2] = p4[bc * 2] + p4[bc * 2 + 1];
        t[3] = p5[bc * 4] + p5[bc * 4 + 1] + p5[bc * 4 + 2] + p5[bc * 4 + 3];
        double npow_i = numel;
        for (int i = 0; i < 4; ++i) {
            double tv = t[i];
            double p = tv, d = npow_i;
            for (int j = 0; j < 3; ++j) {
                acc += (double)coef[ch * 12 + i * 3 + j] * (p / d);
                p *= tv;
                d *= numel;
            }
            npow_i *= numel;
        }
    }
    out[b] = (float)acc;
}

extern "C" void kernel_launch(void* const* d_in, const int* in_sizes, int n_in,
                              void* d_out, int out_size, void* d_ws, size_t ws_size,
                              hipStream_t stream) {
    const float* x    = (const float*)d_in[0];
    const float* w    = (const float*)d_in[1];
    const float* bias = (const float*)d_in[2];
    const float* coef = (const float*)d_in[3];
    float* out = (float*)d_out;

    // head: p2[512*2] p3[512*4] p4[512*2] p5[512*4] doubles (48KB) in first 64KB
    double* p2 = (double*)d_ws;
    double* p3 = p2 + NBC * 2;
    double* p4 = p3 + NBC * 4;
    double* p5 = p4 + NBC * 2;
    const size_t head = 65536;

    const size_t per_mat = (size_t)MATU * 4;                 // 256 KB per packed matrix plane
    size_t avail = (ws_size > head) ? ws_size - head : 0;
    int NC = (int)(avail / (2 * per_mat));                   // Y + M per matrix (512 KB)
    NC &= ~7;                                                // whole batches of 8 channels
    if (NC > 256) NC = 256;                                  // chunk WS <= 128MB (proven-safe)
    if (NC < 8) NC = 8;

    unsigned* Ypk = (unsigned*)((char*)d_ws + head);
    unsigned* Mpk = Ypk + (size_t)NC * MATU;

    for (int bc0 = 0; bc0 < NBC; bc0 += NC) {
        int cur = NBC - bc0;
        if (cur > NC) cur = NC;
        int nb = cur / 8;
        conv_pack<<<dim3(16, nb, 2), 256, 0, stream>>>(x, w, bias, Ypk, bc0 / 8);
        // G1: M = Y*Y ; t2 = tr(M), t3 = sum M_ij * Y_ji
        gemm_mfma<1><<<cur * 4, 256, 0, stream>>>(Ypk, Ypk, Mpk, p2, p3, bc0, cur);
        // G2: P = M*M ; t4 = tr(P), t5 = sum P_ij * Y_ji
        gemm_mfma<2><<<cur * 4, 256, 0, stream>>>(Mpk, Ypk, nullptr, p4, p5, bc0, cur);
    }
    combine<<<1, 64, 0, stream>>>(p2, p3, p4, p5, coef, out);
}

// Round 20
// 226.217 us; speedup vs baseline: 3.6382x; 1.0041x over previous
//
#include <hip/hip_runtime.h>

typedef short short8 __attribute__((ext_vector_type(8)));
typedef float f32x4 __attribute__((ext_vector_type(4)));

#define B_    64
#define CH_   8
#define NBC   512
#define MATU  65536      // elements per padded 256x256 matrix
#define H_    251
#define PADX  76         // conv input tile LDS row stride (floats; 304B = 16B-aligned rows)
#define LDSW  40         // A-plane LDS row stride in ushort (80B): frag reads 2-way max

#define SEL_HI 0x07060302u   // perm(y,x,SEL_HI) = (hi16(y)<<16)|hi16(x)
#define SEL_LO 0x05040100u   // perm(y,x,SEL_LO) = (lo16(y)<<16)|lo16(x)

__device__ inline unsigned short bf16r(float f){
    unsigned u = __float_as_uint(f);
    u += 0x7fffu + ((u >> 16) & 1u);
    return (unsigned short)(u >> 16);
}
__device__ inline float bf16f(unsigned short h){ return __uint_as_float(((unsigned)h) << 16); }
__device__ inline unsigned packsplit(float v){
    unsigned short h = bf16r(v);
    unsigned short l = bf16r(v - bf16f(h));
    return (((unsigned)h) << 16) | (unsigned)l;
}
__device__ inline float unpackf(unsigned u){
    return __uint_as_float(u & 0xffff0000u) + bf16f((unsigned short)(u & 0xffffu));
}

// ---------------- conv: x[b] -> Ypk (packed hi|lo u32, row-major), zero-padded to 256.
// 4 channels per block; row loads hoisted across channels, float4-vectorized staging. ----------------
__global__ __launch_bounds__(256) void conv_pack(const float* __restrict__ x,
                                                 const float* __restrict__ w,
                                                 const float* __restrict__ bias,
                                                 unsigned* __restrict__ Ypk,
                                                 int b_base) {
    __shared__ float xt[69 * PADX];
    __shared__ float wsm[148];                 // 4*36 weights + 4 bias

    int tid = threadIdx.x;
    int tile = blockIdx.x;                     // 0..15
    int lb = blockIdx.y;                       // local batch in chunk
    int cq = blockIdx.z;                       // channel quad 0..1
    int b = b_base + lb;
    int r0 = (tile >> 2) * 64, c0 = (tile & 3) * 64;

    if (tid < 144) wsm[tid] = w[cq * 144 + tid];
    if (tid < 4)   wsm[144 + tid] = bias[cq * 4 + tid];

    const float* xb = x + (size_t)b * 65536;
    // 69 rows x 19 float4-chunks = 1311 items, 6 iterations; chunks fully in-range or fully OOB->0
    for (int idx = tid; idx < 69 * 19; idx += 256) {
        int row = idx / 19, chq = idx - row * 19;
        int gr = r0 + row, gc = c0 + chq * 4;
        float4 v = make_float4(0.f, 0.f, 0.f, 0.f);
        if (gr < 256 && gc < 256) v = *(const float4*)(xb + gr * 256 + gc);
        *(float4*)&xt[row * PADX + chq * 4] = v;
    }
    __syncthreads();

    int tx = tid & 15, ty = tid >> 4;

    float acc[4][4][4];
    #pragma unroll
    for (int cc = 0; cc < 4; ++cc) {
        float bv = wsm[144 + cc];
        #pragma unroll
        for (int i = 0; i < 4; ++i)
            #pragma unroll
            for (int j = 0; j < 4; ++j) acc[cc][i][j] = bv;
    }

    #pragma unroll
    for (int ir = 0; ir < 9; ++ir) {
        float row[9];
        {
            const float* xr = &xt[(ty * 4 + ir) * PADX + tx * 4];   // 16B-aligned
            float4 ra = *(const float4*)xr;
            float4 rb = *(const float4*)(xr + 4);
            row[0] = ra.x; row[1] = ra.y; row[2] = ra.z; row[3] = ra.w;
            row[4] = rb.x; row[5] = rb.y; row[6] = rb.z; row[7] = rb.w;
            row[8] = xr[8];
        }
        #pragma unroll
        for (int cc = 0; cc < 4; ++cc) {
            const float* wc = &wsm[cc * 36];
            #pragma unroll
            for (int i = 0; i < 4; ++i) {
                int u = ir - i;
                if (u >= 0 && u < 6) {
                    #pragma unroll
                    for (int v = 0; v < 6; ++v) {
                        float wv = wc[u * 6 + v];
                        #pragma unroll
                        for (int j = 0; j < 4; ++j) acc[cc][i][j] += row[j + v] * wv;
                    }
                }
            }
        }
    }

    #pragma unroll
    for (int cc = 0; cc < 4; ++cc) {
        int ch = cq * 4 + cc;
        unsigned pk[4][4];
        #pragma unroll
        for (int i = 0; i < 4; ++i) {
            int gr = r0 + ty * 4 + i;
            #pragma unroll
            for (int j = 0; j < 4; ++j) {
                int gc = c0 + tx * 4 + j;
                float v = (gr < H_ && gc < H_) ? acc[cc][i][j] : 0.f;
                pk[i][j] = packsplit(v);
            }
        }
        unsigned* yrow = Ypk + (size_t)(lb * 8 + ch) * MATU;
        #pragma unroll
        for (int i = 0; i < 4; ++i) {
            uint4 v = make_uint4(pk[i][0], pk[i][1], pk[i][2], pk[i][3]);
            *(uint4*)&yrow[(size_t)(r0 + ty * 4 + i) * 256 + c0 + tx * 4] = v;
        }
    }
}

// ---------------- MFMA GEMM out = X*X (split bf16, 3 chains), X = Apk (row-major packed).
// Single-barrier K-loop with FULL double-buffered LDS (A and B planes x2):
//   per step: write staged regs -> LDS[ks&1]; issue next step's global loads; ONE barrier;
//   frag-read + 48 MFMA. Loads span the barrier + MFMA phase (latency hidden in-block).
// Proven layouts/unpack kept: A [128][LDSW] planes, B subtiled [kb:4][col:128][8], v_perm unpack.
// PHASE1 (X=Y): writes M row-major; pdiag=t2=tr(M), pfull=t3=sum M_ij*Y_ji
// PHASE2 (X=M): no writes;          pdiag=t4,       pfull=t5=sum (M*M)_ij*Y_ji
template<int PHASE>
__global__ __launch_bounds__(256, 4) void gemm_mfma(const unsigned* __restrict__ Apk,
                                                    const unsigned* __restrict__ Ypk,
                                                    unsigned* __restrict__ Mpk,
                                                    double* __restrict__ pdiag,
                                                    double* __restrict__ pfull,
                                                    int bc_base, int cur) {
    // two 36864B buffers: [Ahi 10240 | Alo 10240 | Bhi 8192 | Blo 8192]
    __shared__ __align__(16) char smem[73728];
    __shared__ double redbuf[8];

    int tid = threadIdx.x;

    // XCD-colocating bijective remap (cur always a multiple of 8)
    int hw = blockIdx.x;
    int xcd = hw & 7, s = hw >> 3;
    int mpx = cur >> 3;
    int lbc = xcd * mpx + (s >> 2);
    int t4 = s & 3;
    int by = t4 >> 1, bx = t4 & 1;
    int bi = by * 128, bj = bx * 128;
    int bc = bc_base + lbc;

    const unsigned* A = Apk + (size_t)lbc * MATU;

    int wid = tid >> 6, l = tid & 63;
    int wr = wid >> 1, wc = wid & 1;
    int l15 = l & 15, lk = l >> 4;

    f32x4 acc[4][4];
    #pragma unroll
    for (int m = 0; m < 4; ++m)
        #pragma unroll
        for (int n = 0; n < 4; ++n) acc[m][n] = (f32x4){0.f, 0.f, 0.f, 0.f};

    // A-stage mapping: thread covers (row = g>>3, chn = g&7) for g = p*256+tid
    // B-stage mapping: lane owns cols cl+32j (j=0..3), ks kq..kq+3
    const int cl  = tid & 31;
    const int grp = tid >> 5;            // 0..7
    const int kq  = grp * 4;             // 0,4,...,28
    const int kb  = grp >> 1;            // k-block 0..3
    const int koff = (grp & 1) * 4;      // offset within 8-k block

    uint4 qa[4];
    unsigned d[4][4];
    // prologue: load K-step 0 into regs
    #pragma unroll
    for (int p = 0; p < 4; ++p) {
        int g = p * 256 + tid;
        qa[p] = *(const uint4*)(A + (size_t)(bi + (g >> 3)) * 256 + (g & 7) * 4);
    }
    {
        const unsigned* Bp = A + (size_t)kq * 256 + bj + cl;
        #pragma unroll
        for (int i = 0; i < 4; ++i)
            #pragma unroll
            for (int j = 0; j < 4; ++j)
                d[i][j] = Bp[i * 256 + j * 32];
    }

    for (int ks = 0; ks < 8; ++ks) {
        char* sb = smem + (ks & 1) * 36864;
        unsigned short* Ahi = (unsigned short*)sb;
        unsigned short* Alo = (unsigned short*)(sb + 10240);
        unsigned short* Bhi = (unsigned short*)(sb + 20480);
        unsigned short* Blo = (unsigned short*)(sb + 28672);

        // ---- write staged regs to LDS[ks&1] (perm unpack) ----
        #pragma unroll
        for (int p = 0; p < 4; ++p) {
            int g = p * 256 + tid;
            int row = g >> 3, chn = g & 7;
            uint2 hv, lv;
            hv.x = __builtin_amdgcn_perm(qa[p].y, qa[p].x, SEL_HI);
            hv.y = __builtin_amdgcn_perm(qa[p].w, qa[p].z, SEL_HI);
            lv.x = __builtin_amdgcn_perm(qa[p].y, qa[p].x, SEL_LO);
            lv.y = __builtin_amdgcn_perm(qa[p].w, qa[p].z, SEL_LO);
            *(uint2*)&Ahi[row * LDSW + chn * 4] = hv;
            *(uint2*)&Alo[row * LDSW + chn * 4] = lv;
        }
        #pragma unroll
        for (int j = 0; j < 4; ++j) {
            int c = cl + 32 * j;
            uint2 hv, lv;
            hv.x = __builtin_amdgcn_perm(d[1][j], d[0][j], SEL_HI);
            hv.y = __builtin_amdgcn_perm(d[3][j], d[2][j], SEL_HI);
            lv.x = __builtin_amdgcn_perm(d[1][j], d[0][j], SEL_LO);
            lv.y = __builtin_amdgcn_perm(d[3][j], d[2][j], SEL_LO);
            *(uint2*)&Bhi[kb * 1024 + c * 8 + koff] = hv;
            *(uint2*)&Blo[kb * 1024 + c * 8 + koff] = lv;
        }

        // ---- issue NEXT K-step's global loads (latency spans barrier + MFMA phase) ----
        if (ks < 7) {
            int k1 = (ks + 1) * 32;
            #pragma unroll
            for (int p = 0; p < 4; ++p) {
                int g = p * 256 + tid;
                qa[p] = *(const uint4*)(A + (size_t)(bi + (g >> 3)) * 256 + k1 + (g & 7) * 4);
            }
            const unsigned* Bp = A + (size_t)(k1 + kq) * 256 + bj + cl;
            #pragma unroll
            for (int i = 0; i < 4; ++i)
                #pragma unroll
                for (int j = 0; j < 4; ++j)
                    d[i][j] = Bp[i * 256 + j * 32];
        }

        __syncthreads();

        // ---- frag reads + MFMA on LDS[ks&1] ----
        short8 ah[4], al[4], bh[4], bl[4];
        #pragma unroll
        for (int m = 0; m < 4; ++m) {
            int r = wr * 64 + m * 16 + l15;
            ah[m] = *(const short8*)&Ahi[r * LDSW + lk * 8];
            al[m] = *(const short8*)&Alo[r * LDSW + lk * 8];
        }
        #pragma unroll
        for (int n = 0; n < 4; ++n) {
            int c = wc * 64 + n * 16 + l15;
            bh[n] = *(const short8*)&Bhi[lk * 1024 + c * 8];
            bl[n] = *(const short8*)&Blo[lk * 1024 + c * 8];
        }
        #pragma unroll
        for (int m = 0; m < 4; ++m)
            #pragma unroll
            for (int n = 0; n < 4; ++n) {
                acc[m][n] = __builtin_amdgcn_mfma_f32_16x16x32_bf16(ah[m], bh[n], acc[m][n], 0, 0, 0);
                acc[m][n] = __builtin_amdgcn_mfma_f32_16x16x32_bf16(ah[m], bl[n], acc[m][n], 0, 0, 0);
                acc[m][n] = __builtin_amdgcn_mfma_f32_16x16x32_bf16(al[m], bh[n], acc[m][n], 0, 0, 0);
            }
        // no trailing barrier: next iteration writes the OTHER buffer; a wave can only
        // reach the write of buffer p after barrier(ks-1), which postdates all reads of p
    }

    // ---- epilogue: partial traces (+ M write in PHASE1); Y_ji read from row-major Y (contiguous 16B) ----
    const unsigned* Yb = Ypk + (size_t)lbc * MATU;
    unsigned* Mw = (PHASE == 1) ? (Mpk + (size_t)lbc * MATU) : nullptr;
    float s_full = 0.f, s_diag = 0.f;
    #pragma unroll
    for (int m = 0; m < 4; ++m) {
        int rg0 = bi + wr * 64 + m * 16 + lk * 4;
        #pragma unroll
        for (int n = 0; n < 4; ++n) {
            int cg = bj + wc * 64 + n * 16 + l15;
            uint4 yq = *(const uint4*)(Yb + (size_t)cg * 256 + rg0);   // Y[cg][rg0..rg0+3]
            unsigned yu[4] = {yq.x, yq.y, yq.z, yq.w};
            f32x4 v = acc[m][n];
            #pragma unroll
            for (int reg = 0; reg < 4; ++reg) {
                float val = v[reg];
                s_full += val * unpackf(yu[reg]);
                if (rg0 + reg == cg) s_diag += val;
                if (PHASE == 1) Mw[(size_t)(rg0 + reg) * 256 + cg] = packsplit(val);
            }
        }
    }

    // reduce partials
    double df = (double)s_full, dd = (double)s_diag;
    #pragma unroll
    for (int off = 32; off > 0; off >>= 1) {
        df += __shfl_down(df, off, 64);
        dd += __shfl_down(dd, off, 64);
    }
    __syncthreads();
    if (l == 0) { redbuf[wid] = df; redbuf[4 + wid] = dd; }
    __syncthreads();
    if (tid == 0) {
        pfull[(size_t)bc * 4 + by * 2 + bx] =
            redbuf[0] + redbuf[1] + redbuf[2] + redbuf[3];
        if (bx == by)
            pdiag[(size_t)bc * 2 + bx] =
                redbuf[4] + redbuf[5] + redbuf[6] + redbuf[7];
    }
}

// ---------------- combine ----------------
__global__ void combine(const double* __restrict__ p2, const double* __restrict__ p3,
                        const double* __restrict__ p4, const double* __restrict__ p5,
                        const float* __restrict__ coef, float* __restrict__ out) {
    int b = threadIdx.x;
    if (b >= B_) return;
    const double numel = (double)(H_ * H_);
    double acc = 0.0;
    for (int ch = 0; ch < CH_; ++ch) {
        int bc = b * CH_ + ch;
        double t[4];
        t[0] = p2[bc * 2] + p2[bc * 2 + 1];
        t[1] = p3[bc * 4] + p3[bc * 4 + 1] + p3[bc * 4 + 2] + p3[bc * 4 + 3];
        t[2] = p4[bc * 2] + p4[bc * 2 + 1];
        t[3] = p5[bc * 4] + p5[bc * 4 + 1] + p5[bc * 4 + 2] + p5[bc * 4 + 3];
        double npow_i = numel;
        for (int i = 0; i < 4; ++i) {
            double tv = t[i];
            double p = tv, d = npow_i;
            for (int j = 0; j < 3; ++j) {
                acc += (double)coef[ch * 12 + i * 3 + j] * (p / d);
                p *= tv;
                d *= numel;
            }
            npow_i *= numel;
        }
    }
    out[b] = (float)acc;
}

extern "C" void kernel_launch(void* const* d_in, const int* in_sizes, int n_in,
                              void* d_out, int out_size, void* d_ws, size_t ws_size,
                              hipStream_t stream) {
    const float* x    = (const float*)d_in[0];
    const float* w    = (const float*)d_in[1];
    const float* bias = (const float*)d_in[2];
    const float* coef = (const float*)d_in[3];
    float* out = (float*)d_out;

    // head: p2[512*2] p3[512*4] p4[512*2] p5[512*4] doubles (48KB) in first 64KB
    double* p2 = (double*)d_ws;
    double* p3 = p2 + NBC * 2;
    double* p4 = p3 + NBC * 4;
    double* p5 = p4 + NBC * 2;
    const size_t head = 65536;

    const size_t per_mat = (size_t)MATU * 4;                 // 256 KB per packed matrix plane
    size_t avail = (ws_size > head) ? ws_size - head : 0;
    int NC = (int)(avail / (2 * per_mat));                   // Y + M per matrix (512 KB)
    NC &= ~7;                                                // whole batches of 8 channels
    if (NC > 256) NC = 256;                                  // chunk WS <= 128MB (proven-safe)
    if (NC < 8) NC = 8;

    unsigned* Ypk = (unsigned*)((char*)d_ws + head);
    unsigned* Mpk = Ypk + (size_t)NC * MATU;

    for (int bc0 = 0; bc0 < NBC; bc0 += NC) {
        int cur = NBC - bc0;
        if (cur > NC) cur = NC;
        int nb = cur / 8;
        conv_pack<<<dim3(16, nb, 2), 256, 0, stream>>>(x, w, bias, Ypk, bc0 / 8);
        // G1: M = Y*Y ; t2 = tr(M), t3 = sum M_ij * Y_ji
        gemm_mfma<1><<<cur * 4, 256, 0, stream>>>(Ypk, Ypk, Mpk, p2, p3, bc0, cur);
        // G2: P = M*M ; t4 = tr(P), t5 = sum P_ij * Y_ji
        gemm_mfma<2><<<cur * 4, 256, 0, stream>>>(Mpk, Ypk, nullptr, p4, p5, bc0, cur);
    }
    combine<<<1, 64, 0, stream>>>(p2, p3, p4, p5, coef, out);
}